// Round 4
// baseline (807.460 us; speedup 1.0000x reference)
//
#include <hip/hip_runtime.h>
#include <hip/hip_bf16.h>

#define HIDDEN 2048
#define NHEADS 16
#define HEADD  128
#define BATCH  4
#define SEQ    2048
#define MROWS  (BATCH*SEQ)   // 8192
#define NQKV   (3*HIDDEN)    // 6144

typedef __attribute__((ext_vector_type(8))) short bf16x8;
typedef __attribute__((ext_vector_type(4))) short bf16x4;
typedef __attribute__((ext_vector_type(4))) float f32x4;

__device__ inline unsigned short f2bf(float f) {
  unsigned int u = __builtin_bit_cast(unsigned int, f);
  u += 0x7FFF + ((u >> 16) & 1);           // RNE
  return (unsigned short)(u >> 16);
}

__device__ inline void async16(const void* g, void* s) {
  __builtin_amdgcn_global_load_lds(
      (__attribute__((address_space(1))) void*)(g),
      (__attribute__((address_space(3))) void*)(s), 16, 0, 0);
}

// ---------------- fp32 -> bf16 conversion (8 elems/thread) ----------------
__global__ __launch_bounds__(256)
void cvt_f32_bf16(const float* __restrict__ in, unsigned short* __restrict__ out, int n) {
  int i = (blockIdx.x * 256 + threadIdx.x) * 8;
  if (i + 8 <= n) {
    float4 a = *(const float4*)&in[i];
    float4 b = *(const float4*)&in[i + 4];
    unsigned short o[8];
    o[0] = f2bf(a.x); o[1] = f2bf(a.y); o[2] = f2bf(a.z); o[3] = f2bf(a.w);
    o[4] = f2bf(b.x); o[5] = f2bf(b.y); o[6] = f2bf(b.z); o[7] = f2bf(b.w);
    *(uint4*)&out[i] = *(uint4*)o;
  }
}

// ---------------- NT GEMM: C[m][n] = sum_k A[m][k]*Bw[n][k] + bias[n] -----
template<int OUT_BF16>
__global__ __launch_bounds__(256)
void gemm_nt(const unsigned short* __restrict__ A,   // [M][K] bf16
             const unsigned short* __restrict__ Bw,  // [N][K] bf16 (i.e. B^T)
             const float* __restrict__ bias,         // [N] fp32
             void* __restrict__ Cout, int M, int N, int K) {
  constexpr int BM = 128, BN = 128, BK = 32;
  __shared__ __align__(16) unsigned short lA[BM * BK];
  __shared__ __align__(16) unsigned short lB[BN * BK];
  const int t = threadIdx.x;
  const int lane = t & 63, wv = t >> 6;
  const int r = lane & 15, q = lane >> 4;
  const int m0 = blockIdx.y * BM;
  const int n0 = blockIdx.x * BN;
  const int wr = (wv >> 1) * 64;
  const int wc = (wv & 1) * 64;

  f32x4 acc[4][4] = {};

  for (int k0 = 0; k0 < K; k0 += BK) {
    __syncthreads();
    {
      int c = t, row = c >> 2, cc = (c & 3) * 8;
      async16(A + (size_t)(m0 + row) * K + k0 + cc, &lA[c * 8]);
      c = t + 256; row = c >> 2; cc = (c & 3) * 8;
      async16(A + (size_t)(m0 + row) * K + k0 + cc, &lA[c * 8]);
      c = t; row = c >> 2; cc = (c & 3) * 8;
      async16(Bw + (size_t)(n0 + row) * K + k0 + cc, &lB[c * 8]);
      c = t + 256; row = c >> 2; cc = (c & 3) * 8;
      async16(Bw + (size_t)(n0 + row) * K + k0 + cc, &lB[c * 8]);
    }
    __syncthreads();
    bf16x8 af[4], bfv[4];
    for (int i = 0; i < 4; ++i)
      af[i] = *(const bf16x8*)&lA[(wr + i * 16 + r) * BK + q * 8];
    for (int j = 0; j < 4; ++j)
      bfv[j] = *(const bf16x8*)&lB[(wc + j * 16 + r) * BK + q * 8];
    for (int i = 0; i < 4; ++i)
      for (int j = 0; j < 4; ++j)
        acc[i][j] = __builtin_amdgcn_mfma_f32_16x16x32_bf16(af[i], bfv[j], acc[i][j], 0, 0, 0);
  }

  for (int i = 0; i < 4; ++i) {
    int row = m0 + wr + i * 16 + q * 4;
    for (int j = 0; j < 4; ++j) {
      int col = n0 + wc + j * 16 + r;
      float bv = bias[col];
      for (int rr = 0; rr < 4; ++rr) {
        float v = acc[i][j][rr] + bv;
        if (OUT_BF16)
          ((unsigned short*)Cout)[(size_t)(row + rr) * N + col] = f2bf(v);
        else
          ((float*)Cout)[(size_t)(row + rr) * N + col] = v;
      }
    }
  }
}

// ---------------- causal flash attention v4 --------------------------------
// BQ=128, 4 waves x 32 q-rows. Q in regs. Computes S^T (A=K, B=Q) so the
// score C-layout IS the 16x16x16 A-operand layout -> P feeds PV directly
// from registers (no P LDS round-trip). Fixed-max softmax, per-lane row sums.
__global__ __launch_bounds__(256, 2)
void flash_attn(const unsigned short* __restrict__ qkv,  // [8192][6144] bf16
                unsigned short* __restrict__ attn)       // [8192][2048] bf16
{
  // XOR-swizzled: (row,k) of Ks at [row][((k>>3) ^ (row&7))*8 + (k&7)]
  // Vt (d,kv) at [d][((kv>>3) ^ (d&7) ^ ((d>>3)&7))*8 + (kv&7)]
  __shared__ __align__(16) unsigned short Ks[64][128];   // 16 KB
  __shared__ __align__(16) unsigned short Vt[128][64];   // 16 KB

  const int t = threadIdx.x;
  const int lane = t & 63, wv = t >> 6;
  const int r = lane & 15, q = lane >> 4;
  const int b = blockIdx.y >> 4, h = blockIdx.y & 15;
  const int qt = (int)(gridDim.x - 1 - blockIdx.x);  // heavy tiles dispatch first
  const int q0 = qt * 128;

  const size_t rs = NQKV;
  const unsigned short* qbase = qkv + (size_t)(b * SEQ) * rs + h * HEADD;
  const unsigned short* kbase = qbase + HIDDEN;
  const unsigned short* vbase = qbase + 2 * HIDDEN;

  // Q fragments in registers; identical layout serves as MFMA B-operand.
  bf16x8 qf[2][4];
  for (int i = 0; i < 2; ++i)
    for (int ks = 0; ks < 4; ++ks)
      qf[i][ks] = *(const bf16x8*)(qbase +
          (size_t)(q0 + wv * 32 + i * 16 + r) * rs + ks * 32 + q * 8);

  f32x4 accO[2][8] = {};   // O^ tile: row(q)=quad*4+rr, col(d)=n*16+r
  float lsum[2] = {0.f, 0.f};  // per-lane partial row-sum for q-row = i*16+r

  const int ntiles = 2 * qt + 2;
  const int diag0 = 2 * qt;
  const float sc2 = 0.08838834764831845f * 1.4426950408889634f;  // scale*log2e

  const int koct = t & 15, krb = t >> 4;      // K staging ids
  const int bd4 = t & 15, bkv4 = t >> 4;      // V staging ids

  uint4 kreg[4], vreg[4];
  for (int s = 0; s < 4; ++s)
    kreg[s] = *(const uint4*)(kbase + (size_t)(krb + 16 * s) * rs + koct * 8);
  for (int jr = 0; jr < 4; ++jr)
    vreg[jr] = *(const uint4*)(vbase + (size_t)(bkv4 * 4 + jr) * rs + bd4 * 8);

  for (int tk = 0; tk < ntiles; ++tk) {
    __syncthreads();  // prior tile's LDS reads done before overwrite
    for (int s = 0; s < 4; ++s) {
      int row = krb + 16 * s;
      int cb = koct ^ (row & 7);
      *(uint4*)&Ks[row][cb * 8] = kreg[s];
    }
    for (int jj = 0; jj < 8; ++jj) {
      int d = bd4 * 8 + jj;
      int cb = (bkv4 >> 1) ^ jj ^ (bd4 & 7);
      unsigned short tmp[4];
      for (int jr = 0; jr < 4; ++jr)
        tmp[jr] = ((const unsigned short*)&vreg[jr])[jj];
      *(uint2*)&Vt[d][cb * 8 + (bkv4 & 1) * 4] = *(const uint2*)tmp;
    }
    __syncthreads();
    if (tk + 1 < ntiles) {  // prefetch next tile; lands during compute
      for (int s = 0; s < 4; ++s)
        kreg[s] = *(const uint4*)(kbase + (size_t)((tk + 1) * 64 + krb + 16 * s) * rs + koct * 8);
      for (int jr = 0; jr < 4; ++jr)
        vreg[jr] = *(const uint4*)(vbase + (size_t)((tk + 1) * 64 + bkv4 * 4 + jr) * rs + bd4 * 8);
    }

    // --- S^T = K_tile(A) x Q(B): tiles [kv=j][q=i]; lane: q=r, kv=q*4+rr ---
    f32x4 s2[2][4] = {};
    for (int ks = 0; ks < 4; ++ks) {
      bf16x8 af[4];
      for (int j = 0; j < 4; ++j) {
        int row = j * 16 + r;
        int cb = (ks * 4 + q) ^ (r & 7);
        af[j] = *(const bf16x8*)&Ks[row][cb * 8];
      }
      for (int i = 0; i < 2; ++i)
        for (int j = 0; j < 4; ++j)
          s2[i][j] = __builtin_amdgcn_mfma_f32_16x16x32_bf16(af[j], qf[i][ks], s2[i][j], 0, 0, 0);
    }

    // --- mask + exp2; pack P directly into 16x16x16 A-operands ---
    const bool diag = (tk >= diag0);
    bf16x4 pf[2][4];
    for (int i = 0; i < 2; ++i) {
      int qp = q0 + wv * 32 + i * 16 + r;
      for (int j = 0; j < 4; ++j) {
        unsigned short pk[4];
        for (int rr = 0; rr < 4; ++rr) {
          float v = s2[i][j][rr] * sc2;
          if (diag) {
            int kvp = tk * 64 + j * 16 + q * 4 + rr;
            if (kvp > qp) v = -1e30f;
          }
          float p = __builtin_amdgcn_exp2f(v);
          lsum[i] += p;
          pk[rr] = f2bf(p);
        }
        pf[i][j] = *(const bf16x4*)pk;
      }
    }

    // --- O^ += P(A,reg) x V(B from Vt): 16x16x16, K=16 per j-block ---
    for (int j = 0; j < 4; ++j)
      for (int n = 0; n < 8; ++n) {
        int d = n * 16 + r;
        int o = j * 2 + (q >> 1);
        int cb = o ^ (r & 7) ^ ((n * 2 + (r >> 3)) & 7);
        bf16x4 bv = *(const bf16x4*)&Vt[d][cb * 8 + (q & 1) * 4];
        for (int i = 0; i < 2; ++i)
          accO[i][n] = __builtin_amdgcn_mfma_f32_16x16x16bf16_1k(pf[i][j], bv, accO[i][n], 0, 0, 0);
      }
  }

  // epilogue: finish row sums (reduce across quads), then write O
  float linv[2];
  for (int i = 0; i < 2; ++i) {
    float l = lsum[i];
    l += __shfl_xor(l, 16, 64);
    l += __shfl_xor(l, 32, 64);
    linv[i] = 1.0f / l;
  }
  for (int i = 0; i < 2; ++i)
    for (int rr = 0; rr < 4; ++rr) {
      int row = q0 + wv * 32 + i * 16 + q * 4 + rr;
      float inv = __shfl(linv[i], q * 4 + rr, 16);
      size_t obase = (size_t)(b * SEQ + row) * HIDDEN + h * HEADD;
      for (int n = 0; n < 8; ++n)
        attn[obase + n * 16 + r] = f2bf(accO[i][n][rr] * inv);
    }
}

// ---------------------------------------------------------------------------
extern "C" void kernel_launch(void* const* d_in, const int* in_sizes, int n_in,
                              void* d_out, int out_size, void* d_ws, size_t ws_size,
                              hipStream_t stream) {
  const float* hs      = (const float*)d_in[0];
  const float* w_qkv   = (const float*)d_in[1];
  const float* b_qkv   = (const float*)d_in[2];
  const float* w_dense = (const float*)d_in[3];
  const float* b_dense = (const float*)d_in[4];

  char* ws = (char*)d_ws;
  unsigned short* hsb  = (unsigned short*)ws;                            // 32 MB (reused as attn)
  unsigned short* wqb  = (unsigned short*)(ws + 33554432);               // 24 MB (reused as w_dense)
  unsigned short* qkvb = (unsigned short*)(ws + 33554432 + 25165824);    // 96 MB
  unsigned short* attnb = hsb;
  unsigned short* wdb   = wqb;

  cvt_f32_bf16<<<MROWS * HIDDEN / 2048, 256, 0, stream>>>(hs, hsb, MROWS * HIDDEN);
  cvt_f32_bf16<<<NQKV * HIDDEN / 2048, 256, 0, stream>>>(w_qkv, wqb, NQKV * HIDDEN);

  gemm_nt<1><<<dim3(NQKV / 128, MROWS / 128), 256, 0, stream>>>(
      hsb, wqb, b_qkv, qkvb, MROWS, NQKV, HIDDEN);

  flash_attn<<<dim3(SEQ / 128, BATCH * NHEADS), 256, 0, stream>>>(qkvb, attnb);

  cvt_f32_bf16<<<HIDDEN * HIDDEN / 2048, 256, 0, stream>>>(w_dense, wdb, HIDDEN * HIDDEN);

  gemm_nt<0><<<dim3(HIDDEN / 128, MROWS / 128), 256, 0, stream>>>(
      attnb, wdb, b_dense, d_out, MROWS, HIDDEN, HIDDEN);
}